// Round 9
// baseline (232.807 us; speedup 1.0000x reference)
//
#include <hip/hip_runtime.h>
#include <hip/hip_bf16.h>

typedef unsigned short u16;
typedef unsigned int u32;
typedef short s16x8 __attribute__((ext_vector_type(8)));
typedef short s16x4 __attribute__((ext_vector_type(4)));
typedef float f32x4 __attribute__((ext_vector_type(4)));

#define NB 8
#define NT 2048
#define NC 512
#define NH 512

#if __has_builtin(__builtin_amdgcn_mfma_f32_16x16x16_bf16)
#define MFMA_PV(va, pb, c) __builtin_amdgcn_mfma_f32_16x16x16_bf16(va, pb, c, 0, 0, 0)
#else
#define MFMA_PV(va, pb, c) __builtin_amdgcn_mfma_f32_16x16x16bf16_1k(va, pb, c, 0, 0, 0)
#endif

__device__ __forceinline__ u16 f2bf(float f) {
  unsigned u = __float_as_uint(f);
  u += 0x7FFFu + ((u >> 16) & 1u);   // round-to-nearest-even
  return (u16)(u >> 16);
}

// async 16B global->LDS (dest = wave-uniform base + lane*16, src per-lane)
__device__ __forceinline__ void gld16(const u16* src, u16* lds_dst) {
  __builtin_amdgcn_global_load_lds(
      (const __attribute__((address_space(1))) u32*)src,
      (__attribute__((address_space(3))) u32*)lds_dst, 16, 0, 0);
}

// ---------------- K0: W [C][H] fp32 -> WT [H][C] bf16 (all 3 in one launch) --
__global__ __launch_bounds__(256) void wt_kernel(const float* __restrict__ Wq,
                                                 const float* __restrict__ Wk,
                                                 const float* __restrict__ Wv,
                                                 u16* __restrict__ WqT,
                                                 u16* __restrict__ WkT,
                                                 u16* __restrict__ WvT) {
  __shared__ float tile[32][33];
  const float* W = (blockIdx.z == 0) ? Wq : (blockIdx.z == 1) ? Wk : Wv;
  u16* WT = (blockIdx.z == 0) ? WqT : (blockIdx.z == 1) ? WkT : WvT;
  const int x = threadIdx.x & 31;
  const int y = threadIdx.x >> 5;
  const int k0 = blockIdx.x * 32, h0 = blockIdx.y * 32;
#pragma unroll
  for (int p = 0; p < 4; ++p)
    tile[y + 8 * p][x] = W[(size_t)(k0 + y + 8 * p) * NH + h0 + x];
  __syncthreads();
#pragma unroll
  for (int p = 0; p < 4; ++p)
    WT[(size_t)(h0 + y + 8 * p) * NC + k0 + x] = f2bf(tile[x][y + 8 * p]);
}

// ---------------- K1: Y = X @ W + b  (q,k,v in one launch; T14 dbuf) --------
__global__ __launch_bounds__(256) void proj_kernel(const float* __restrict__ Xq,
                                                   const float* __restrict__ Xk,
                                                   const float* __restrict__ Xv,
                                                   const u16* __restrict__ WqT,
                                                   const u16* __restrict__ WkT,
                                                   const u16* __restrict__ WvT,
                                                   const float* __restrict__ bq,
                                                   const float* __restrict__ bk,
                                                   const float* __restrict__ bv,
                                                   u16* __restrict__ Yq,
                                                   u16* __restrict__ Yk,
                                                   u16* __restrict__ Yv) {
  __shared__ __align__(16) u16 Asub[2][128 * 40];
  __shared__ __align__(16) u16 Bsub[2][128 * 40];
  const int zz = blockIdx.z;
  const float* X = (zz == 0) ? Xq : (zz == 1) ? Xk : Xv;
  const u16* WT = (zz == 0) ? WqT : (zz == 1) ? WkT : WvT;
  const float* bias = (zz == 0) ? bq : (zz == 1) ? bk : bv;
  u16* Y = (zz == 0) ? Yq : (zz == 1) ? Yk : Yv;

  const int t = threadIdx.x;
  const int lane = t & 63;
  const int w = t >> 6;
  const int l16 = lane & 15;
  const int ko8 = (lane >> 4) * 8;
  const int m0 = blockIdx.y * 128;
  const int n0 = blockIdx.x * 128;
  const int wr = (w >> 1) * 64, wc = (w & 1) * 64;
  f32x4 acc[4][4] = {};

  float4 areg[4];
  int4 breg[2];
#define PLOAD(kt)                                                              \
  {                                                                            \
    const int k0_ = (kt) * 32;                                                 \
    _Pragma("unroll")                                                          \
    for (int p = 0; p < 4; ++p) {                                              \
      int c = t + 256 * p;                                                     \
      areg[p] = *(const float4*)&X[(size_t)(m0 + (c >> 3)) * NC + k0_ + (c & 7) * 4]; \
    }                                                                          \
    _Pragma("unroll")                                                          \
    for (int p = 0; p < 2; ++p) {                                              \
      int c = t + 256 * p;                                                     \
      breg[p] = *(const int4*)&WT[(size_t)(n0 + (c >> 2)) * NC + k0_ + (c & 3) * 8];  \
    }                                                                          \
  }
#define PWRITE(buf)                                                            \
  {                                                                            \
    _Pragma("unroll")                                                          \
    for (int p = 0; p < 4; ++p) {                                              \
      int c = t + 256 * p;                                                     \
      ushort4 bb;                                                              \
      bb.x = f2bf(areg[p].x); bb.y = f2bf(areg[p].y);                          \
      bb.z = f2bf(areg[p].z); bb.w = f2bf(areg[p].w);                          \
      *(ushort4*)&Asub[buf][(c >> 3) * 40 + (c & 7) * 4] = bb;                 \
    }                                                                          \
    _Pragma("unroll")                                                          \
    for (int p = 0; p < 2; ++p) {                                              \
      int c = t + 256 * p;                                                     \
      *(int4*)&Bsub[buf][(c >> 2) * 40 + (c & 3) * 8] = breg[p];               \
    }                                                                          \
  }

  PLOAD(0)
  PWRITE(0)
  __syncthreads();

  int pb = 0;
  for (int kt = 0; kt < 16; ++kt) {
    if (kt < 15) PLOAD(kt + 1)
    s16x8 af[4], bf[4];
#pragma unroll
    for (int i = 0; i < 4; ++i)
      af[i] = *(const s16x8*)&Asub[pb][(wr + i * 16 + l16) * 40 + ko8];
#pragma unroll
    for (int j = 0; j < 4; ++j)
      bf[j] = *(const s16x8*)&Bsub[pb][(wc + j * 16 + l16) * 40 + ko8];
#pragma unroll
    for (int i = 0; i < 4; ++i)
#pragma unroll
      for (int j = 0; j < 4; ++j)
        acc[i][j] = __builtin_amdgcn_mfma_f32_16x16x32_bf16(af[i], bf[j], acc[i][j], 0, 0, 0);
    if (kt < 15) PWRITE(pb ^ 1)
    __syncthreads();
    pb ^= 1;
  }
#undef PLOAD
#undef PWRITE
  const int rg = (lane >> 4) * 4;
#pragma unroll
  for (int i = 0; i < 4; ++i)
#pragma unroll
    for (int j = 0; j < 4; ++j) {
      const int col = n0 + wc + j * 16 + l16;
      const float bcol = bias[col];
#pragma unroll
      for (int jj = 0; jj < 4; ++jj) {
        const int row = m0 + wr + i * 16 + rg + jj;
        Y[(size_t)row * NH + col] = f2bf(acc[i][j][jj] + bcol);
      }
    }
}

// ---------------- K2: Vp [B][T][H] -> VpT [B][H][Tswz] (granule-interleaved) -
// Per 32-kv block, kv j stored at position perm(j) = ((j&15)>>2)*8 + (j>>4)*4
// + (j&3): 8B granule pairs (kv 4g..4g+3 | kv 16+4g..16+4g+3). A 16B chunk at
// granule-pair g then holds exactly the two 16x16x16 A-frag granules.
__global__ __launch_bounds__(256) void vt_kernel(const u16* __restrict__ Vp,
                                                 u16* __restrict__ VpT) {
  __shared__ u16 tile[32][33];
  const int x = threadIdx.x & 31;
  const int y = threadIdx.x >> 5;
  const int t0 = blockIdx.x * 32, h0 = blockIdx.y * 32, b = blockIdx.z;
  const u16* src = Vp + (size_t)b * NT * NH;
  u16* dst = VpT + (size_t)b * NH * NT;
  const int xp = ((x & 15) >> 2) * 8 + (x >> 4) * 4 + (x & 3);  // perm within 32
#pragma unroll
  for (int p = 0; p < 4; ++p)
    tile[y + 8 * p][x] = src[(size_t)(t0 + y + 8 * p) * NH + h0 + x];
  __syncthreads();
#pragma unroll
  for (int p = 0; p < 4; ++p)
    dst[(size_t)(h0 + y + 8 * p) * NT + t0 + xp] = tile[x][y + 8 * p];
}

// ---------------- K3a: flash partial, QB=128, 2-way kv-split ----------------
// grid (NB=8, NT/128=16, 2). block 512 = 8 waves, each owns 16 q rows.
// KVBLK=32, double-buffered K+V LDS (128 KB).
// QK: S^T[32kv][16q] via 16x16x32 (lane q=l16, kv = g*4+j / 16+g*4+j).
// PV: per h-tile ONE ds_read_b128 of pre-swizzled V gives both 16x16x16
// A-frags; pv[0..3]/pv[4..7] pack DIRECTLY into B-frags (zero shuffles).
// Per-lane partial l (reduced once in epilogue). T13 defer-max THR=8.
__global__ __launch_bounds__(512, 2) void flash_partial(const u16* __restrict__ Qp,
                                                        const u16* __restrict__ Kp,
                                                        const u16* __restrict__ VpT,
                                                        float* __restrict__ O0,
                                                        float* __restrict__ O1,
                                                        float* __restrict__ mlws) {
  __shared__ __align__(16) u16 Klds[2][32 * 512];   // 32 KB each
  __shared__ __align__(16) u16 Vlds[2][32 * 512];   // 32 KB each

  const int t = threadIdx.x;
  const int lane = t & 63;
  const int w = t >> 6;
  const int l16 = lane & 15;
  const int g = lane >> 4;
  const int g8 = g * 8;
  const int b = blockIdx.x;
  const int q0 = blockIdx.y * 128;
  const int z = blockIdx.z;
  const int qg = q0 + w * 16 + l16;
  const float kscale = 0.044194173824159216f;  // 1/sqrt(512)

  s16x8 qf[16];
  {
    const u16* qrow = Qp + (size_t)(b * NT + qg) * NH;
#pragma unroll
    for (int ks = 0; ks < 16; ++ks)
      qf[ks] = *(const s16x8*)&qrow[ks * 32 + g8];
  }

  f32x4 oacc[32] = {};                 // O^T: h = ht*16 + g*4 + j, q = l16
  float m_run = -1e30f, l_run = 0.f;   // l_run is PER-LANE partial (8 kv slots)

  const u16* kbat = Kp + (size_t)(b * NT + z * 1024) * NH;
  const u16* vbat = VpT + (size_t)b * NH * NT + z * 1024;

#define STAGE(buf, it)                                                         \
  {                                                                            \
    _Pragma("unroll")                                                          \
    for (int r = 0; r < 4; ++r) {                                              \
      const int i = w * 4 + r;  /* 0..31 */                                    \
      gld16(kbat + (size_t)((it) * 32 + ((i & 1) << 4) + l16) * NH             \
                 + ((i >> 1) << 5) + g8,                                       \
            &Klds[buf][i * 512]);                                              \
      gld16(vbat + (size_t)(i * 16 + l16) * NT + (it) * 32 + g8,               \
            &Vlds[buf][i * 512]);                                              \
    }                                                                          \
  }

  STAGE(0, 0)
  __syncthreads();

  int pb = 0;
  for (int it = 0; it < 32; ++it) {
    if (it < 31) STAGE(pb ^ 1, it + 1)
    // ---- QK^T: S^T[32 kv][16 q] ----
    f32x4 s0 = {}, s1 = {};
    __builtin_amdgcn_s_setprio(1);
#pragma unroll
    for (int ks = 0; ks < 16; ++ks) {
      s16x8 kf0 = *(const s16x8*)&Klds[pb][(ks * 2 + 0) * 512 + lane * 8];
      s16x8 kf1 = *(const s16x8*)&Klds[pb][(ks * 2 + 1) * 512 + lane * 8];
      s0 = __builtin_amdgcn_mfma_f32_16x16x32_bf16(kf0, qf[ks], s0, 0, 0, 0);
      s1 = __builtin_amdgcn_mfma_f32_16x16x32_bf16(kf1, qf[ks], s1, 0, 0, 0);
    }
    __builtin_amdgcn_s_setprio(0);
    // ---- softmax (in-register; lane's q = l16) ----
    float pv[8];
#pragma unroll
    for (int j = 0; j < 4; ++j) { pv[j] = s0[j] * kscale; pv[4 + j] = s1[j] * kscale; }
    float mx = pv[0];
#pragma unroll
    for (int j = 1; j < 8; ++j) mx = fmaxf(mx, pv[j]);
    mx = fmaxf(mx, __shfl_xor(mx, 16, 64));
    mx = fmaxf(mx, __shfl_xor(mx, 32, 64));
    if (__any(mx > m_run + 8.f)) {     // T13 defer-max
      const float m_new = fmaxf(m_run, mx);
      const float scale = __expf(m_run - m_new);
#pragma unroll
      for (int ht = 0; ht < 32; ++ht) {
        oacc[ht][0] *= scale; oacc[ht][1] *= scale;
        oacc[ht][2] *= scale; oacc[ht][3] *= scale;
      }
      l_run *= scale;
      m_run = m_new;
    }
    float ts = 0.f;
#pragma unroll
    for (int j = 0; j < 8; ++j) { pv[j] = __expf(pv[j] - m_run); ts += pv[j]; }
    l_run += ts;                       // per-lane partial; reduced in epilogue
    // ---- P direct pack: two 16x16x16 B-frags (k = g*4+j, col = l16) ----
    union { u32 u[2]; s16x4 v; } plo, phi;
    plo.u[0] = ((u32)f2bf(pv[1]) << 16) | f2bf(pv[0]);
    plo.u[1] = ((u32)f2bf(pv[3]) << 16) | f2bf(pv[2]);
    phi.u[0] = ((u32)f2bf(pv[5]) << 16) | f2bf(pv[4]);
    phi.u[1] = ((u32)f2bf(pv[7]) << 16) | f2bf(pv[6]);
    // ---- PV: O^T[h][q] += V^T[h][kv] @ P^T[kv][q], two K=16 slices ----
    __builtin_amdgcn_s_setprio(1);
#pragma unroll
    for (int ht = 0; ht < 32; ++ht) {
      s16x8 vf = *(const s16x8*)&Vlds[pb][ht * 512 + lane * 8];
      s16x4 vlo = __builtin_shufflevector(vf, vf, 0, 1, 2, 3);
      s16x4 vhi = __builtin_shufflevector(vf, vf, 4, 5, 6, 7);
      oacc[ht] = MFMA_PV(vlo, plo.v, oacc[ht]);
      oacc[ht] = MFMA_PV(vhi, phi.v, oacc[ht]);
    }
    __builtin_amdgcn_s_setprio(0);
    __syncthreads();
    pb ^= 1;
  }
  // ---- epilogue: UNNORMALIZED O + (m,l) ----
  float* obase = (z ? O1 : O0) + (size_t)(b * NT + qg) * NH;
#pragma unroll
  for (int ht = 0; ht < 32; ++ht) {
    float4 st;
    st.x = oacc[ht][0]; st.y = oacc[ht][1];
    st.z = oacc[ht][2]; st.w = oacc[ht][3];
    *(float4*)&obase[ht * 16 + g * 4] = st;
  }
  float lt = l_run;
  lt += __shfl_xor(lt, 16, 64);
  lt += __shfl_xor(lt, 32, 64);
  if (g == 0) {
    const size_t row = (size_t)b * NT + qg;
    mlws[row * 4 + z * 2 + 0] = m_run;
    mlws[row * 4 + z * 2 + 1] = lt;
  }
#undef STAGE
}

// ---------------- K3b: merge two kv-half partials ----------------
__global__ __launch_bounds__(128) void merge_kernel(float* __restrict__ out,
                                                    const float* __restrict__ O1,
                                                    const float* __restrict__ mlws) {
  const size_t row = blockIdx.x;
  const float m0 = mlws[row * 4 + 0], l0 = mlws[row * 4 + 1];
  const float m1 = mlws[row * 4 + 2], l1 = mlws[row * 4 + 3];
  const float m = fmaxf(m0, m1);
  const float a0 = __expf(m0 - m), a1 = __expf(m1 - m);
  const float inv = 1.f / (a0 * l0 + a1 * l1);
  const float c0 = a0 * inv, c1 = a1 * inv;
  const size_t idx = row * NH + threadIdx.x * 4;
  float4 o0 = *(const float4*)&out[idx];
  float4 o1 = *(const float4*)&O1[idx];
  float4 r;
  r.x = c0 * o0.x + c1 * o1.x;
  r.y = c0 * o0.y + c1 * o1.y;
  r.z = c0 * o0.z + c1 * o1.z;
  r.w = c0 * o0.w + c1 * o1.w;
  *(float4*)&out[idx] = r;
}

// ---------------- K3-fallback: single-pass flash (if ws too small) ----------
__global__ __launch_bounds__(256, 1) void flash_kernel(const u16* __restrict__ Qp,
                                                       const u16* __restrict__ Kp,
                                                       const u16* __restrict__ VpT,
                                                       float* __restrict__ out) {
  __shared__ __align__(16) u16 Klds[2][32 * 512];
  __shared__ __align__(16) u16 Vlds[2][32 * 512];

  const int t = threadIdx.x;
  const int lane = t & 63;
  const int w = t >> 6;
  const int l16 = lane & 15;
  const int g = lane >> 4;
  const int g8 = g * 8;
  const int b = blockIdx.x;
  const int q0 = blockIdx.y * 64;
  const int qg = q0 + w * 16 + l16;
  const float kscale = 0.044194173824159216f;

  s16x8 qf[16];
  {
    const u16* qrow = Qp + (size_t)(b * NT + qg) * NH;
#pragma unroll
    for (int ks = 0; ks < 16; ++ks)
      qf[ks] = *(const s16x8*)&qrow[ks * 32 + g8];
  }
  f32x4 oacc[32] = {};
  float m_run = -1e30f, l_run = 0.f;
  const u16* kbat = Kp + (size_t)b * NT * NH;
  const u16* vbat = VpT + (size_t)b * NH * NT;

#pragma unroll
  for (int r = 0; r < 8; ++r) {
    const int i = w * 8 + r;
    gld16(kbat + (size_t)(((i & 1) << 4) + l16) * NH + ((i >> 1) << 5) + g8,
          &Klds[0][i * 512]);
    gld16(vbat + (size_t)(i * 16 + l16) * NT + g8, &Vlds[0][i * 512]);
  }
  __syncthreads();

  int pb = 0;
  for (int it = 0; it < 64; ++it) {
    if (it < 63) {
      const int kv1 = (it + 1) * 32;
      const int nb = pb ^ 1;
#pragma unroll
      for (int r = 0; r < 8; ++r) {
        const int i = w * 8 + r;
        gld16(kbat + (size_t)(kv1 + ((i & 1) << 4) + l16) * NH + ((i >> 1) << 5) + g8,
              &Klds[nb][i * 512]);
        gld16(vbat + (size_t)(i * 16 + l16) * NT + kv1 + g8, &Vlds[nb][i * 512]);
      }
    }
    f32x4 s0 = {}, s1 = {};
#pragma unroll
    for (int ks = 0; ks < 16; ++ks) {
      s16x8 kf0 = *(const s16x8*)&Klds[pb][(ks * 2 + 0) * 512 + lane * 8];
      s16x8 kf1 = *(const s16x8*)&Klds[pb][(ks * 2 + 1) * 512 + lane * 8];
      s0 = __builtin_amdgcn_mfma_f32_16x16x32_bf16(kf0, qf[ks], s0, 0, 0, 0);
      s1 = __builtin_amdgcn_mfma_f32_16x16x32_bf16(kf1, qf[ks], s1, 0, 0, 0);
    }
    float pv[8];
#pragma unroll
    for (int j = 0; j < 4; ++j) { pv[j] = s0[j] * kscale; pv[4 + j] = s1[j] * kscale; }
    float mx = pv[0];
#pragma unroll
    for (int j = 1; j < 8; ++j) mx = fmaxf(mx, pv[j]);
    mx = fmaxf(mx, __shfl_xor(mx, 16, 64));
    mx = fmaxf(mx, __shfl_xor(mx, 32, 64));
    if (__any(mx > m_run + 8.f)) {
      const float m_new = fmaxf(m_run, mx);
      const float scale = __expf(m_run - m_new);
#pragma unroll
      for (int ht = 0; ht < 32; ++ht) {
        oacc[ht][0] *= scale; oacc[ht][1] *= scale;
        oacc[ht][2] *= scale; oacc[ht][3] *= scale;
      }
      l_run *= scale;
      m_run = m_new;
    }
    float ts = 0.f;
#pragma unroll
    for (int j = 0; j < 8; ++j) { pv[j] = __expf(pv[j] - m_run); ts += pv[j]; }
    l_run += ts;
    union { u32 u[2]; s16x4 v; } plo, phi;
    plo.u[0] = ((u32)f2bf(pv[1]) << 16) | f2bf(pv[0]);
    plo.u[1] = ((u32)f2bf(pv[3]) << 16) | f2bf(pv[2]);
    phi.u[0] = ((u32)f2bf(pv[5]) << 16) | f2bf(pv[4]);
    phi.u[1] = ((u32)f2bf(pv[7]) << 16) | f2bf(pv[6]);
#pragma unroll
    for (int ht = 0; ht < 32; ++ht) {
      s16x8 vf = *(const s16x8*)&Vlds[pb][ht * 512 + lane * 8];
      s16x4 vlo = __builtin_shufflevector(vf, vf, 0, 1, 2, 3);
      s16x4 vhi = __builtin_shufflevector(vf, vf, 4, 5, 6, 7);
      oacc[ht] = MFMA_PV(vlo, plo.v, oacc[ht]);
      oacc[ht] = MFMA_PV(vhi, phi.v, oacc[ht]);
    }
    __syncthreads();
    pb ^= 1;
  }
  float lt = l_run;
  lt += __shfl_xor(lt, 16, 64);
  lt += __shfl_xor(lt, 32, 64);
  const float inv = 1.f / lt;
  float* obase = out + (size_t)(b * NT + qg) * NH;
#pragma unroll
  for (int ht = 0; ht < 32; ++ht) {
    float4 st;
    st.x = oacc[ht][0] * inv; st.y = oacc[ht][1] * inv;
    st.z = oacc[ht][2] * inv; st.w = oacc[ht][3] * inv;
    *(float4*)&obase[ht * 16 + g * 4] = st;
  }
}

extern "C" void kernel_launch(void* const* d_in, const int* in_sizes, int n_in,
                              void* d_out, int out_size, void* d_ws, size_t ws_size,
                              hipStream_t stream) {
  (void)in_sizes; (void)n_in; (void)out_size;
  const float* q  = (const float*)d_in[0];
  const float* k  = (const float*)d_in[1];
  const float* v  = (const float*)d_in[2];
  const float* Wq = (const float*)d_in[3];
  const float* bq = (const float*)d_in[4];
  const float* Wk = (const float*)d_in[5];
  const float* bk = (const float*)d_in[6];
  const float* Wv = (const float*)d_in[7];
  const float* bv = (const float*)d_in[8];
  float* out = (float*)d_out;

  u16* ws   = (u16*)d_ws;
  u16* WqT  = ws;
  u16* WkT  = WqT + (size_t)NC * NH;
  u16* WvT  = WkT + (size_t)NC * NH;
  u16* Qp   = WvT + (size_t)NC * NH;
  u16* Kp   = Qp + (size_t)NB * NT * NH;
  u16* Vp   = Kp + (size_t)NB * NT * NH;
  u16* VpT  = Vp + (size_t)NB * NT * NH;
  u16* endb = VpT + (size_t)NB * NT * NH;
  float* O1   = (float*)endb;
  float* mlws = O1 + (size_t)NB * NT * NH;
  const size_t need = (size_t)((char*)(mlws + (size_t)NB * NT * 4) - (char*)d_ws);

  wt_kernel<<<dim3(16, 16, 3), 256, 0, stream>>>(Wq, Wk, Wv, WqT, WkT, WvT);

  proj_kernel<<<dim3(4, 128, 3), 256, 0, stream>>>(q, k, v, WqT, WkT, WvT,
                                                   bq, bk, bv, Qp, Kp, Vp);

  vt_kernel<<<dim3(64, 16, NB), 256, 0, stream>>>(Vp, VpT);

  if (ws_size >= need) {
    flash_partial<<<dim3(NB, NT / 128, 2), 512, 0, stream>>>(Qp, Kp, VpT, out, O1, mlws);
    merge_kernel<<<dim3(NB * NT), 128, 0, stream>>>(out, O1, mlws);
  } else {
    flash_kernel<<<dim3(NB, NT / 64), 256, 0, stream>>>(Qp, Kp, VpT, out);
  }
}

// Round 10
// 214.733 us; speedup vs baseline: 1.0842x; 1.0842x over previous
//
#include <hip/hip_runtime.h>
#include <hip/hip_bf16.h>

typedef unsigned short u16;
typedef unsigned int u32;
typedef short s16x8 __attribute__((ext_vector_type(8)));
typedef float f32x4 __attribute__((ext_vector_type(4)));

#define NB 8
#define NT 2048
#define NC 512
#define NH 512

__device__ __forceinline__ u16 f2bf(float f) {
  unsigned u = __float_as_uint(f);
  u += 0x7FFFu + ((u >> 16) & 1u);   // round-to-nearest-even
  return (u16)(u >> 16);
}

// async 16B global->LDS (dest = wave-uniform base + lane*16, src per-lane)
__device__ __forceinline__ void gld16(const u16* src, u16* lds_dst) {
  __builtin_amdgcn_global_load_lds(
      (const __attribute__((address_space(1))) u32*)src,
      (__attribute__((address_space(3))) u32*)lds_dst, 16, 0, 0);
}

// ---------------- K0: W [C][H] fp32 -> WT [H][C] bf16 (all 3 in one launch) --
__global__ __launch_bounds__(256) void wt_kernel(const float* __restrict__ Wq,
                                                 const float* __restrict__ Wk,
                                                 const float* __restrict__ Wv,
                                                 u16* __restrict__ WqT,
                                                 u16* __restrict__ WkT,
                                                 u16* __restrict__ WvT) {
  __shared__ float tile[32][33];
  const float* W = (blockIdx.z == 0) ? Wq : (blockIdx.z == 1) ? Wk : Wv;
  u16* WT = (blockIdx.z == 0) ? WqT : (blockIdx.z == 1) ? WkT : WvT;
  const int x = threadIdx.x & 31;
  const int y = threadIdx.x >> 5;
  const int k0 = blockIdx.x * 32, h0 = blockIdx.y * 32;
#pragma unroll
  for (int p = 0; p < 4; ++p)
    tile[y + 8 * p][x] = W[(size_t)(k0 + y + 8 * p) * NH + h0 + x];
  __syncthreads();
#pragma unroll
  for (int p = 0; p < 4; ++p)
    WT[(size_t)(h0 + y + 8 * p) * NC + k0 + x] = f2bf(tile[x][y + 8 * p]);
}

// ---------------- K1: Y = X @ W + b  (q,k,v in one launch; T14 dbuf) --------
__global__ __launch_bounds__(256) void proj_kernel(const float* __restrict__ Xq,
                                                   const float* __restrict__ Xk,
                                                   const float* __restrict__ Xv,
                                                   const u16* __restrict__ WqT,
                                                   const u16* __restrict__ WkT,
                                                   const u16* __restrict__ WvT,
                                                   const float* __restrict__ bq,
                                                   const float* __restrict__ bk,
                                                   const float* __restrict__ bv,
                                                   u16* __restrict__ Yq,
                                                   u16* __restrict__ Yk,
                                                   u16* __restrict__ Yv) {
  __shared__ __align__(16) u16 Asub[2][128 * 40];
  __shared__ __align__(16) u16 Bsub[2][128 * 40];
  const int zz = blockIdx.z;
  const float* X = (zz == 0) ? Xq : (zz == 1) ? Xk : Xv;
  const u16* WT = (zz == 0) ? WqT : (zz == 1) ? WkT : WvT;
  const float* bias = (zz == 0) ? bq : (zz == 1) ? bk : bv;
  u16* Y = (zz == 0) ? Yq : (zz == 1) ? Yk : Yv;

  const int t = threadIdx.x;
  const int lane = t & 63;
  const int w = t >> 6;
  const int l16 = lane & 15;
  const int ko8 = (lane >> 4) * 8;
  const int m0 = blockIdx.y * 128;
  const int n0 = blockIdx.x * 128;
  const int wr = (w >> 1) * 64, wc = (w & 1) * 64;
  f32x4 acc[4][4] = {};

  float4 areg[4];
  int4 breg[2];
#define PLOAD(kt)                                                              \
  {                                                                            \
    const int k0_ = (kt) * 32;                                                 \
    _Pragma("unroll")                                                          \
    for (int p = 0; p < 4; ++p) {                                              \
      int c = t + 256 * p;                                                     \
      areg[p] = *(const float4*)&X[(size_t)(m0 + (c >> 3)) * NC + k0_ + (c & 7) * 4]; \
    }                                                                          \
    _Pragma("unroll")                                                          \
    for (int p = 0; p < 2; ++p) {                                              \
      int c = t + 256 * p;                                                     \
      breg[p] = *(const int4*)&WT[(size_t)(n0 + (c >> 2)) * NC + k0_ + (c & 3) * 8];  \
    }                                                                          \
  }
#define PWRITE(buf)                                                            \
  {                                                                            \
    _Pragma("unroll")                                                          \
    for (int p = 0; p < 4; ++p) {                                              \
      int c = t + 256 * p;                                                     \
      ushort4 bb;                                                              \
      bb.x = f2bf(areg[p].x); bb.y = f2bf(areg[p].y);                          \
      bb.z = f2bf(areg[p].z); bb.w = f2bf(areg[p].w);                          \
      *(ushort4*)&Asub[buf][(c >> 3) * 40 + (c & 7) * 4] = bb;                 \
    }                                                                          \
    _Pragma("unroll")                                                          \
    for (int p = 0; p < 2; ++p) {                                              \
      int c = t + 256 * p;                                                     \
      *(int4*)&Bsub[buf][(c >> 2) * 40 + (c & 3) * 8] = breg[p];               \
    }                                                                          \
  }

  PLOAD(0)
  PWRITE(0)
  __syncthreads();

  int pb = 0;
  for (int kt = 0; kt < 16; ++kt) {
    if (kt < 15) PLOAD(kt + 1)
    s16x8 af[4], bf[4];
#pragma unroll
    for (int i = 0; i < 4; ++i)
      af[i] = *(const s16x8*)&Asub[pb][(wr + i * 16 + l16) * 40 + ko8];
#pragma unroll
    for (int j = 0; j < 4; ++j)
      bf[j] = *(const s16x8*)&Bsub[pb][(wc + j * 16 + l16) * 40 + ko8];
#pragma unroll
    for (int i = 0; i < 4; ++i)
#pragma unroll
      for (int j = 0; j < 4; ++j)
        acc[i][j] = __builtin_amdgcn_mfma_f32_16x16x32_bf16(af[i], bf[j], acc[i][j], 0, 0, 0);
    if (kt < 15) PWRITE(pb ^ 1)
    __syncthreads();
    pb ^= 1;
  }
#undef PLOAD
#undef PWRITE
  const int rg = (lane >> 4) * 4;
#pragma unroll
  for (int i = 0; i < 4; ++i)
#pragma unroll
    for (int j = 0; j < 4; ++j) {
      const int col = n0 + wc + j * 16 + l16;
      const float bcol = bias[col];
#pragma unroll
      for (int jj = 0; jj < 4; ++jj) {
        const int row = m0 + wr + i * 16 + rg + jj;
        Y[(size_t)row * NH + col] = f2bf(acc[i][j][jj] + bcol);
      }
    }
}

// ---------------- K2: Vp [B][T][H] bf16 -> VpT [B][H][T] bf16 ----------------
__global__ __launch_bounds__(256) void vt_kernel(const u16* __restrict__ Vp,
                                                 u16* __restrict__ VpT) {
  __shared__ u16 tile[32][33];
  const int x = threadIdx.x & 31;
  const int y = threadIdx.x >> 5;
  const int t0 = blockIdx.x * 32, h0 = blockIdx.y * 32, b = blockIdx.z;
  const u16* src = Vp + (size_t)b * NT * NH;
  u16* dst = VpT + (size_t)b * NH * NT;
#pragma unroll
  for (int p = 0; p < 4; ++p)
    tile[y + 8 * p][x] = src[(size_t)(t0 + y + 8 * p) * NH + h0 + x];
  __syncthreads();
#pragma unroll
  for (int p = 0; p < 4; ++p)
    dst[(size_t)(h0 + y + 8 * p) * NT + t0 + x] = tile[x][y + 8 * p];
}

// ---------------- K3a: flash partial, QB=128, 2-way kv-split ----------------
// grid (NB=8, NT/128=16, 2). block 512 = 8 waves, each owns 16 q rows.
// KVBLK=32, double-buffered K+V LDS (128 KB).
// K STAGING PERMUTATION: tile kb row l16 holds K[kv = (l16>>2)*8 + kb*4 +
// (l16&3)]. MFMA out-row = A-row, so lane (g,j) gets S for kv = g*8+kb*4+j:
// pv[0..7] = kv g*8..g*8+7 CONTIGUOUS = the verified 16x16x32 B-frag layout
// (word w = kv pair g*8+2w). Zero shuffles, PV stays 32 full-K MFMAs.
// Per-lane partial l (epilogue-reduced); T13 defer-max THR=8; T5 setprio.
__global__ __launch_bounds__(512, 2) void flash_partial(const u16* __restrict__ Qp,
                                                        const u16* __restrict__ Kp,
                                                        const u16* __restrict__ VpT,
                                                        float* __restrict__ O0,
                                                        float* __restrict__ O1,
                                                        float* __restrict__ mlws) {
  __shared__ __align__(16) u16 Klds[2][32 * 512];   // 32 KB each
  __shared__ __align__(16) u16 Vlds[2][32 * 512];   // 32 KB each

  const int t = threadIdx.x;
  const int lane = t & 63;
  const int w = t >> 6;
  const int l16 = lane & 15;
  const int g = lane >> 4;
  const int g8 = g * 8;
  const int b = blockIdx.x;
  const int q0 = blockIdx.y * 128;
  const int z = blockIdx.z;
  const int qg = q0 + w * 16 + l16;
  const int kperm = (l16 >> 2) * 8 + (l16 & 3);   // K staging row permutation
  const float kscale = 0.044194173824159216f;     // 1/sqrt(512)

  s16x8 qf[16];
  {
    const u16* qrow = Qp + (size_t)(b * NT + qg) * NH;
#pragma unroll
    for (int ks = 0; ks < 16; ++ks)
      qf[ks] = *(const s16x8*)&qrow[ks * 32 + g8];
  }

  f32x4 oacc[32] = {};                 // O^T: h = ht*16 + g*4 + j, q = l16
  float m_run = -1e30f, l_run = 0.f;   // l_run is PER-LANE partial (8 kv slots)

  const u16* kbat = Kp + (size_t)(b * NT + z * 1024) * NH;
  const u16* vbat = VpT + (size_t)b * NH * NT + z * 1024;

#define STAGE(buf, it)                                                         \
  {                                                                            \
    _Pragma("unroll")                                                          \
    for (int r = 0; r < 4; ++r) {                                              \
      const int i = w * 4 + r;  /* 0..31 */                                    \
      /* K frag i: ks=i>>1, kb=i&1; row = kperm + kb*4 (permuted) */           \
      gld16(kbat + (size_t)((it) * 32 + kperm + ((i & 1) << 2)) * NH           \
                 + ((i >> 1) << 5) + g8,                                       \
            &Klds[buf][i * 512]);                                              \
      /* V frag i=ht: V^T[ht*16+l16][kv0+g*8..+7] */                           \
      gld16(vbat + (size_t)(i * 16 + l16) * NT + (it) * 32 + g8,               \
            &Vlds[buf][i * 512]);                                              \
    }                                                                          \
  }

  STAGE(0, 0)
  __syncthreads();

  int pb = 0;
  for (int it = 0; it < 32; ++it) {
    if (it < 31) STAGE(pb ^ 1, it + 1)
    // ---- QK^T: S^T[32 kv][16 q], kv permuted per-lane-contiguous ----
    f32x4 s0 = {}, s1 = {};
    __builtin_amdgcn_s_setprio(1);
#pragma unroll
    for (int ks = 0; ks < 16; ++ks) {
      s16x8 kf0 = *(const s16x8*)&Klds[pb][(ks * 2 + 0) * 512 + lane * 8];
      s16x8 kf1 = *(const s16x8*)&Klds[pb][(ks * 2 + 1) * 512 + lane * 8];
      s0 = __builtin_amdgcn_mfma_f32_16x16x32_bf16(kf0, qf[ks], s0, 0, 0, 0);
      s1 = __builtin_amdgcn_mfma_f32_16x16x32_bf16(kf1, qf[ks], s1, 0, 0, 0);
    }
    __builtin_amdgcn_s_setprio(0);
    // ---- softmax: lane holds kv g*8+j (s0) and g*8+4+j (s1), q=l16 ----
    float pv[8];
#pragma unroll
    for (int j = 0; j < 4; ++j) { pv[j] = s0[j] * kscale; pv[4 + j] = s1[j] * kscale; }
    float mx = pv[0];
#pragma unroll
    for (int j = 1; j < 8; ++j) mx = fmaxf(mx, pv[j]);
    mx = fmaxf(mx, __shfl_xor(mx, 16, 64));
    mx = fmaxf(mx, __shfl_xor(mx, 32, 64));
    if (__any(mx > m_run + 8.f)) {     // T13 defer-max
      const float m_new = fmaxf(m_run, mx);
      const float scale = __expf(m_run - m_new);
#pragma unroll
      for (int ht = 0; ht < 32; ++ht) {
        oacc[ht][0] *= scale; oacc[ht][1] *= scale;
        oacc[ht][2] *= scale; oacc[ht][3] *= scale;
      }
      l_run *= scale;
      m_run = m_new;
    }
    float ts = 0.f;
#pragma unroll
    for (int j = 0; j < 8; ++j) { pv[j] = __expf(pv[j] - m_run); ts += pv[j]; }
    l_run += ts;                       // per-lane partial; epilogue-reduced
    // ---- P direct pack: 16x16x32 B-frag, word w = kv pair g*8+2w ----
    union { u32 u[4]; s16x8 v; } pf;
    pf.u[0] = ((u32)f2bf(pv[1]) << 16) | f2bf(pv[0]);
    pf.u[1] = ((u32)f2bf(pv[3]) << 16) | f2bf(pv[2]);
    pf.u[2] = ((u32)f2bf(pv[5]) << 16) | f2bf(pv[4]);
    pf.u[3] = ((u32)f2bf(pv[7]) << 16) | f2bf(pv[6]);
    // ---- PV: O^T[h][q] += V^T[h][kv] @ P^T[kv][q] ----
    __builtin_amdgcn_s_setprio(1);
#pragma unroll
    for (int ht = 0; ht < 32; ++ht) {
      s16x8 vf = *(const s16x8*)&Vlds[pb][ht * 512 + lane * 8];
      oacc[ht] = __builtin_amdgcn_mfma_f32_16x16x32_bf16(vf, pf.v, oacc[ht], 0, 0, 0);
    }
    __builtin_amdgcn_s_setprio(0);
    __syncthreads();
    pb ^= 1;
  }
  // ---- epilogue: UNNORMALIZED O + (m,l) ----
  float* obase = (z ? O1 : O0) + (size_t)(b * NT + qg) * NH;
#pragma unroll
  for (int ht = 0; ht < 32; ++ht) {
    float4 st;
    st.x = oacc[ht][0]; st.y = oacc[ht][1];
    st.z = oacc[ht][2]; st.w = oacc[ht][3];
    *(float4*)&obase[ht * 16 + g * 4] = st;
  }
  float lt = l_run;
  lt += __shfl_xor(lt, 16, 64);
  lt += __shfl_xor(lt, 32, 64);
  if (g == 0) {
    const size_t row = (size_t)b * NT + qg;
    mlws[row * 4 + z * 2 + 0] = m_run;
    mlws[row * 4 + z * 2 + 1] = lt;
  }
#undef STAGE
}

// ---------------- K3b: merge two kv-half partials ----------------
__global__ __launch_bounds__(128) void merge_kernel(float* __restrict__ out,
                                                    const float* __restrict__ O1,
                                                    const float* __restrict__ mlws) {
  const size_t row = blockIdx.x;
  const float m0 = mlws[row * 4 + 0], l0 = mlws[row * 4 + 1];
  const float m1 = mlws[row * 4 + 2], l1 = mlws[row * 4 + 3];
  const float m = fmaxf(m0, m1);
  const float a0 = __expf(m0 - m), a1 = __expf(m1 - m);
  const float inv = 1.f / (a0 * l0 + a1 * l1);
  const float c0 = a0 * inv, c1 = a1 * inv;
  const size_t idx = row * NH + threadIdx.x * 4;
  float4 o0 = *(const float4*)&out[idx];
  float4 o1 = *(const float4*)&O1[idx];
  float4 r;
  r.x = c0 * o0.x + c1 * o1.x;
  r.y = c0 * o0.y + c1 * o1.y;
  r.z = c0 * o0.z + c1 * o1.z;
  r.w = c0 * o0.w + c1 * o1.w;
  *(float4*)&out[idx] = r;
}

// ---------------- K3-fallback: single-pass flash (if ws too small) ----------
__global__ __launch_bounds__(256, 1) void flash_kernel(const u16* __restrict__ Qp,
                                                       const u16* __restrict__ Kp,
                                                       const u16* __restrict__ VpT,
                                                       float* __restrict__ out) {
  __shared__ __align__(16) u16 Klds[2][32 * 512];
  __shared__ __align__(16) u16 Vlds[2][32 * 512];

  const int t = threadIdx.x;
  const int lane = t & 63;
  const int w = t >> 6;
  const int l16 = lane & 15;
  const int g = lane >> 4;
  const int g8 = g * 8;
  const int b = blockIdx.x;
  const int q0 = blockIdx.y * 64;
  const int qg = q0 + w * 16 + l16;
  const int kperm = (l16 >> 2) * 8 + (l16 & 3);
  const float kscale = 0.044194173824159216f;

  s16x8 qf[16];
  {
    const u16* qrow = Qp + (size_t)(b * NT + qg) * NH;
#pragma unroll
    for (int ks = 0; ks < 16; ++ks)
      qf[ks] = *(const s16x8*)&qrow[ks * 32 + g8];
  }
  f32x4 oacc[32] = {};
  float m_run = -1e30f, l_run = 0.f;
  const u16* kbat = Kp + (size_t)b * NT * NH;
  const u16* vbat = VpT + (size_t)b * NH * NT;

#pragma unroll
  for (int r = 0; r < 8; ++r) {
    const int i = w * 8 + r;
    gld16(kbat + (size_t)(kperm + ((i & 1) << 2)) * NH + ((i >> 1) << 5) + g8,
          &Klds[0][i * 512]);
    gld16(vbat + (size_t)(i * 16 + l16) * NT + g8, &Vlds[0][i * 512]);
  }
  __syncthreads();

  int pb = 0;
  for (int it = 0; it < 64; ++it) {
    if (it < 63) {
      const int kv1 = (it + 1) * 32;
      const int nb = pb ^ 1;
#pragma unroll
      for (int r = 0; r < 8; ++r) {
        const int i = w * 8 + r;
        gld16(kbat + (size_t)(kv1 + kperm + ((i & 1) << 2)) * NH + ((i >> 1) << 5) + g8,
              &Klds[nb][i * 512]);
        gld16(vbat + (size_t)(i * 16 + l16) * NT + kv1 + g8, &Vlds[nb][i * 512]);
      }
    }
    f32x4 s0 = {}, s1 = {};
#pragma unroll
    for (int ks = 0; ks < 16; ++ks) {
      s16x8 kf0 = *(const s16x8*)&Klds[pb][(ks * 2 + 0) * 512 + lane * 8];
      s16x8 kf1 = *(const s16x8*)&Klds[pb][(ks * 2 + 1) * 512 + lane * 8];
      s0 = __builtin_amdgcn_mfma_f32_16x16x32_bf16(kf0, qf[ks], s0, 0, 0, 0);
      s1 = __builtin_amdgcn_mfma_f32_16x16x32_bf16(kf1, qf[ks], s1, 0, 0, 0);
    }
    float pv[8];
#pragma unroll
    for (int j = 0; j < 4; ++j) { pv[j] = s0[j] * kscale; pv[4 + j] = s1[j] * kscale; }
    float mx = pv[0];
#pragma unroll
    for (int j = 1; j < 8; ++j) mx = fmaxf(mx, pv[j]);
    mx = fmaxf(mx, __shfl_xor(mx, 16, 64));
    mx = fmaxf(mx, __shfl_xor(mx, 32, 64));
    if (__any(mx > m_run + 8.f)) {
      const float m_new = fmaxf(m_run, mx);
      const float scale = __expf(m_run - m_new);
#pragma unroll
      for (int ht = 0; ht < 32; ++ht) {
        oacc[ht][0] *= scale; oacc[ht][1] *= scale;
        oacc[ht][2] *= scale; oacc[ht][3] *= scale;
      }
      l_run *= scale;
      m_run = m_new;
    }
    float ts = 0.f;
#pragma unroll
    for (int j = 0; j < 8; ++j) { pv[j] = __expf(pv[j] - m_run); ts += pv[j]; }
    l_run += ts;
    union { u32 u[4]; s16x8 v; } pf;
    pf.u[0] = ((u32)f2bf(pv[1]) << 16) | f2bf(pv[0]);
    pf.u[1] = ((u32)f2bf(pv[3]) << 16) | f2bf(pv[2]);
    pf.u[2] = ((u32)f2bf(pv[5]) << 16) | f2bf(pv[4]);
    pf.u[3] = ((u32)f2bf(pv[7]) << 16) | f2bf(pv[6]);
#pragma unroll
    for (int ht = 0; ht < 32; ++ht) {
      s16x8 vf = *(const s16x8*)&Vlds[pb][ht * 512 + lane * 8];
      oacc[ht] = __builtin_amdgcn_mfma_f32_16x16x32_bf16(vf, pf.v, oacc[ht], 0, 0, 0);
    }
    __syncthreads();
    pb ^= 1;
  }
  float lt = l_run;
  lt += __shfl_xor(lt, 16, 64);
  lt += __shfl_xor(lt, 32, 64);
  const float inv = 1.f / lt;
  float* obase = out + (size_t)(b * NT + qg) * NH;
#pragma unroll
  for (int ht = 0; ht < 32; ++ht) {
    float4 st;
    st.x = oacc[ht][0] * inv; st.y = oacc[ht][1] * inv;
    st.z = oacc[ht][2] * inv; st.w = oacc[ht][3] * inv;
    *(float4*)&obase[ht * 16 + g * 4] = st;
  }
}

extern "C" void kernel_launch(void* const* d_in, const int* in_sizes, int n_in,
                              void* d_out, int out_size, void* d_ws, size_t ws_size,
                              hipStream_t stream) {
  (void)in_sizes; (void)n_in; (void)out_size;
  const float* q  = (const float*)d_in[0];
  const float* k  = (const float*)d_in[1];
  const float* v  = (const float*)d_in[2];
  const float* Wq = (const float*)d_in[3];
  const float* bq = (const float*)d_in[4];
  const float* Wk = (const float*)d_in[5];
  const float* bk = (const float*)d_in[6];
  const float* Wv = (const float*)d_in[7];
  const float* bv = (const float*)d_in[8];
  float* out = (float*)d_out;

  u16* ws   = (u16*)d_ws;
  u16* WqT  = ws;
  u16* WkT  = WqT + (size_t)NC * NH;
  u16* WvT  = WkT + (size_t)NC * NH;
  u16* Qp   = WvT + (size_t)NC * NH;
  u16* Kp   = Qp + (size_t)NB * NT * NH;
  u16* Vp   = Kp + (size_t)NB * NT * NH;
  u16* VpT  = Vp + (size_t)NB * NT * NH;
  u16* endb = VpT + (size_t)NB * NT * NH;
  float* O1   = (float*)endb;
  float* mlws = O1 + (size_t)NB * NT * NH;
  const size_t need = (size_t)((char*)(mlws + (size_t)NB * NT * 4) - (char*)d_ws);

  wt_kernel<<<dim3(16, 16, 3), 256, 0, stream>>>(Wq, Wk, Wv, WqT, WkT, WvT);

  proj_kernel<<<dim3(4, 128, 3), 256, 0, stream>>>(q, k, v, WqT, WkT, WvT,
                                                   bq, bk, bv, Qp, Kp, Vp);

  vt_kernel<<<dim3(64, 16, NB), 256, 0, stream>>>(Vp, VpT);

  if (ws_size >= need) {
    flash_partial<<<dim3(NB, NT / 128, 2), 512, 0, stream>>>(Qp, Kp, VpT, out, O1, mlws);
    merge_kernel<<<dim3(NB * NT), 128, 0, stream>>>(out, O1, mlws);
  } else {
    flash_kernel<<<dim3(NB, NT / 64), 256, 0, stream>>>(Qp, Kp, VpT, out);
  }
}